// Round 4
// baseline (69.892 us; speedup 1.0000x reference)
//
#include <hip/hip_runtime.h>
#include <hip/hip_cooperative_groups.h>

namespace cg = cooperative_groups;

#define MARGIN 0.1f
#define B 512
#define P 4
#define N 64
#define D 1024
#define NV (P + N)     // 68 score vectors per batch row
#define GRID 256       // 1 block/CU -> cooperative co-residency guaranteed
#define REP (B / GRID) // 2 rows per block

// 1024 threads = 16 waves. Each block computes partial sums for 2 batch
// rows; grid-wide sync; block 0 does the deterministic final mean.
__global__ __launch_bounds__(1024) void loss_kernel(
    const float* __restrict__ q,     // [B, D]
    const float* __restrict__ pos,   // [B, P, D]
    const float* __restrict__ neg,   // [B, N, D]
    float* __restrict__ partial,     // [B] (d_ws; fully rewritten every call)
    float* __restrict__ out)         // [1]
{
    const int tid  = threadIdx.x;
    const int lane = tid & 63;
    const int wave = tid >> 6;       // 0..15

    __shared__ float scores[NV];     // [0..3]=pos, [4..67]=neg
    __shared__ float wsum[4];

    for (int rep = 0; rep < REP; ++rep) {
        const int b = (int)blockIdx.x + rep * GRID;

        // Each lane keeps 16 query floats (4 x float4), coalesced 1KB/load.
        const float4* q4 = (const float4*)(q + (size_t)b * D);
        float4 qv[4];
#pragma unroll
        for (int i = 0; i < 4; ++i) qv[i] = q4[i * 64 + lane];

        // 68 vectors over 16 waves.
        for (int v = wave; v < NV; v += 16) {
            const float* vec = (v < P)
                ? (pos + ((size_t)b * P + v) * D)
                : (neg + ((size_t)b * N + (v - P)) * D);
            const float4* v4 = (const float4*)vec;
            float acc = 0.0f;
#pragma unroll
            for (int i = 0; i < 4; ++i) {
                float4 x = v4[i * 64 + lane];
                acc += qv[i].x * x.x + qv[i].y * x.y + qv[i].z * x.z + qv[i].w * x.w;
            }
#pragma unroll
            for (int off = 32; off > 0; off >>= 1)
                acc += __shfl_down(acc, off, 64);
            if (lane == 0) scores[v] = acc;
        }
        __syncthreads();

        // Pairwise: 4*64 = 256 pairs on waves 0..3.
        if (wave < 4) {
            float ps  = scores[wave];
            float ns  = scores[P + lane];
            float val = fmaxf(MARGIN - ps + ns, 0.0f);
#pragma unroll
            for (int off = 32; off > 0; off >>= 1)
                val += __shfl_down(val, off, 64);
            if (lane == 0) wsum[wave] = val;
        }
        __syncthreads();

        if (tid == 0) {
            float s = wsum[0] + wsum[1] + wsum[2] + wsum[3];
            __hip_atomic_store(&partial[b], s, __ATOMIC_RELAXED,
                               __HIP_MEMORY_SCOPE_AGENT);
        }
        // No extra sync needed: rep+1's scores writes only start after this
        // rep's sync above, and wsum rewrites are gated by rep+1's first sync.
    }

    // Grid-wide barrier (device-scope fences included).
    cg::this_grid().sync();

    // Block 0, wave 0: deterministic reduction of the 512 partials.
    if (blockIdx.x == 0 && wave == 0) {
        float v = 0.0f;
#pragma unroll
        for (int k = 0; k < 8; ++k)
            v += __hip_atomic_load(&partial[lane + 64 * k], __ATOMIC_RELAXED,
                                   __HIP_MEMORY_SCOPE_AGENT);
#pragma unroll
        for (int off = 32; off > 0; off >>= 1)
            v += __shfl_down(v, off, 64);
        if (lane == 0)
            out[0] = v / (float)(B * P * N);
    }
}

extern "C" void kernel_launch(void* const* d_in, const int* in_sizes, int n_in,
                              void* d_out, int out_size, void* d_ws, size_t ws_size,
                              hipStream_t stream) {
    const float* q   = (const float*)d_in[0];   // [512,1024]
    const float* pos = (const float*)d_in[1];   // [512,4,1024]
    const float* neg = (const float*)d_in[2];   // [512,64,1024]
    float* out       = (float*)d_out;
    float* partial   = (float*)d_ws;            // 512 floats

    void* args[] = { (void*)&q, (void*)&pos, (void*)&neg,
                     (void*)&partial, (void*)&out };
    hipLaunchCooperativeKernel((const void*)loss_kernel,
                               dim3(GRID), dim3(1024), args, 0, stream);
}

// Round 5
// 28.951 us; speedup vs baseline: 2.4142x; 2.4142x over previous
//
#include <hip/hip_runtime.h>

#define MARGIN 0.1f
#define B 512
#define P 4
#define N 64
#define D 1024
#define NV (P + N)   // 68 score vectors per batch row

// One block per batch row b. 1024 threads = 16 waves.
// Wave w computes vectors 4w..4w+3 as TWO PAIRS (8 loads in flight,
// two interleaved shfl-reduce chains); waves 0-3 take the 64..67 tail.
__global__ __launch_bounds__(1024) void scores_kernel(
    const float* __restrict__ q,     // [B, D]
    const float* __restrict__ pos,   // [B, P, D]
    const float* __restrict__ neg,   // [B, N, D]
    float* __restrict__ partial)     // [B]
{
    const int b    = blockIdx.x;
    const int tid  = threadIdx.x;
    const int lane = tid & 63;
    const int wave = tid >> 6;       // 0..15

    // Each lane keeps 16 query floats (4 x float4), coalesced 1KB/load.
    const float4* q4 = (const float4*)(q + (size_t)b * D);
    float4 qv[4];
#pragma unroll
    for (int i = 0; i < 4; ++i) qv[i] = q4[i * 64 + lane];

    __shared__ float scores[NV];     // [0..3]=pos, [4..67]=neg

    const float* posb = pos + (size_t)b * P * D;
    const float* negb = neg + (size_t)b * N * D;
#define VPTR(v) ((const float4*)(((v) < P) ? (posb + (size_t)(v) * D) \
                                           : (negb + (size_t)((v) - P) * D)))

    const int v0 = 4 * wave;
#pragma unroll
    for (int pr = 0; pr < 2; ++pr) {
        const int va = v0 + 2 * pr, vb = va + 1;
        const float4* pa = VPTR(va);
        const float4* pb = VPTR(vb);
        float4 xa[4], xb[4];
#pragma unroll
        for (int i = 0; i < 4; ++i) xa[i] = pa[i * 64 + lane];
#pragma unroll
        for (int i = 0; i < 4; ++i) xb[i] = pb[i * 64 + lane];
        float aa = 0.0f, ab = 0.0f;
#pragma unroll
        for (int i = 0; i < 4; ++i) {
            aa += qv[i].x * xa[i].x + qv[i].y * xa[i].y
                + qv[i].z * xa[i].z + qv[i].w * xa[i].w;
            ab += qv[i].x * xb[i].x + qv[i].y * xb[i].y
                + qv[i].z * xb[i].z + qv[i].w * xb[i].w;
        }
        // two interleaved 64-lane reductions (independent -> ILP)
#pragma unroll
        for (int off = 32; off > 0; off >>= 1) {
            aa += __shfl_down(aa, off, 64);
            ab += __shfl_down(ab, off, 64);
        }
        if (lane == 0) { scores[va] = aa; scores[vb] = ab; }
    }
    if (wave < 4) {                  // tail vectors 64..67
        const int v = 64 + wave;
        const float4* pv = VPTR(v);
        float4 x[4];
#pragma unroll
        for (int i = 0; i < 4; ++i) x[i] = pv[i * 64 + lane];
        float acc = 0.0f;
#pragma unroll
        for (int i = 0; i < 4; ++i)
            acc += qv[i].x * x[i].x + qv[i].y * x[i].y
                 + qv[i].z * x[i].z + qv[i].w * x[i].w;
#pragma unroll
        for (int off = 32; off > 0; off >>= 1)
            acc += __shfl_down(acc, off, 64);
        if (lane == 0) scores[v] = acc;
    }
    __syncthreads();

    // Pairwise: 4*64 = 256 pairs on waves 0..3 (one pair per thread).
    __shared__ float wsum[4];
    if (wave < 4) {
        float ps  = scores[wave];            // pos index
        float ns  = scores[P + lane];        // neg index
        float val = fmaxf(MARGIN - ps + ns, 0.0f);
#pragma unroll
        for (int off = 32; off > 0; off >>= 1)
            val += __shfl_down(val, off, 64);
        if (lane == 0) wsum[wave] = val;
    }
    __syncthreads();
    if (tid == 0)
        partial[b] = wsum[0] + wsum[1] + wsum[2] + wsum[3];
}

// Deterministic final reduction: one wave, 8 partials per lane, no syncs.
__global__ __launch_bounds__(64) void finalize_kernel(
    const float* __restrict__ partial, float* __restrict__ out)
{
    const int lane = threadIdx.x;
    float v = 0.0f;
#pragma unroll
    for (int k = 0; k < 8; ++k)
        v += partial[lane + 64 * k];
#pragma unroll
    for (int off = 32; off > 0; off >>= 1)
        v += __shfl_down(v, off, 64);
    if (lane == 0)
        out[0] = v / (float)(B * P * N);
}

extern "C" void kernel_launch(void* const* d_in, const int* in_sizes, int n_in,
                              void* d_out, int out_size, void* d_ws, size_t ws_size,
                              hipStream_t stream) {
    const float* q   = (const float*)d_in[0];   // [512,1024]
    const float* pos = (const float*)d_in[1];   // [512,4,1024]
    const float* neg = (const float*)d_in[2];   // [512,64,1024]
    float* out       = (float*)d_out;
    float* partial   = (float*)d_ws;            // 512 floats

    scores_kernel<<<B, 1024, 0, stream>>>(q, pos, neg, partial);
    finalize_kernel<<<1, 64, 0, stream>>>(partial, out);
}